// Round 17
// baseline (648.482 us; speedup 1.0000x reference)
//
#include <hip/hip_runtime.h>
#include <hip/hip_bf16.h>
#include <math.h>

#define B_TOTAL 65536

typedef __attribute__((ext_vector_type(8))) short short8v;   // 8 bf16 (4 VGPRs)
typedef __attribute__((ext_vector_type(4))) float f32x4;

__device__ __forceinline__ unsigned short f2bf(float f) {
    union { float f; unsigned u; } v; v.f = f;
    unsigned r = v.u + 0x7FFF + ((v.u >> 16) & 1);   // RNE
    return (unsigned short)(r >> 16);
}

__device__ __forceinline__ unsigned pk2(float a, float b) {
    float2 t; t.x = a; t.y = b;
    __hip_bfloat162 h = __float22bfloat162_rn(t);    // v_cvt_pk_bf16_f32
    union { __hip_bfloat162 h; unsigned u; } c; c.h = h;
    return c.u;
}

// Abramowitz-Stegun 7.1.26 with v_rcp_f32 (rcp rel-err ~1e-7 << formula err 1.5e-7)
__device__ __forceinline__ float erf_fast(float x) {
    float ax = fabsf(x);
    float t = __builtin_amdgcn_rcpf(fmaf(0.3275911f, ax, 1.0f));
    float y = t * (0.254829592f + t * (-0.284496736f + t * (1.421413741f
              + t * (-1.453152027f + t * 1.061405429f))));
    float r = 1.0f - y * __expf(-ax * ax);
    return copysignf(r, x);
}

__device__ __forceinline__ float gelu_exact(float x) {
    return 0.5f * x * (1.0f + erf_fast(x * 0.70710678118654752440f));
}

__device__ __forceinline__ void glds16(const void* g, void* l) {
    __builtin_amdgcn_global_load_lds(
        (const __attribute__((address_space(1))) unsigned int*)g,
        (__attribute__((address_space(3))) unsigned int*)l, 16, 0, 0);
}

// ============== converter: weights -> fragment-linear bf16 in ws ==============
__global__ void convert_weights(const float* __restrict__ W1, const float* __restrict__ W2,
                                const float* __restrict__ gW1,
                                unsigned short* __restrict__ W1L, unsigned short* __restrict__ W2T,
                                unsigned short* __restrict__ gW1T)
{
    int t = blockIdx.x * 256 + threadIdx.x;
    if (t < 65536) {
        int l = t & 63, nt = (t >> 6) & 7, step = (t >> 9) & 15, hd = t >> 13;
        int n = nt * 16 + (l & 15);
        int k = step * 32 + 8 * (l >> 4);
        const float* s = W1 + (size_t)hd * 65536 + (size_t)k * 128 + n;
        short8v o;
        #pragma unroll
        for (int j = 0; j < 8; ++j) o[j] = (short)f2bf(s[(size_t)j * 128]);
        *(short8v*)(W1L + (size_t)t * 8) = o;
    } else if (t < 65536 + 8192) {
        int u = t - 65536;
        int l = u & 63, nt = (u >> 6) & 3, kb = (u >> 8) & 3, hd = u >> 10;
        int m = 16 * nt + (l & 15);
        int k = 32 * kb + 8 * (l >> 4);
        const float* s = W2 + (size_t)hd * 8192 + (size_t)k * 64 + m;
        short8v o;
        #pragma unroll
        for (int j = 0; j < 8; ++j) o[j] = (short)f2bf(s[(size_t)j * 64]);
        *(short8v*)(W2T + (size_t)u * 8) = o;
    } else if (t < 65536 + 8192 + 65536) {
        int u = t - 73728;
        int l = u & 63, nt = (u >> 6) & 31, s0 = u >> 11;
        int n = 16 * nt + (l & 15);
        int k = 32 * s0 + 8 * (l >> 4);
        const float* s = gW1 + (size_t)k * 512 + n;
        short8v o;
        #pragma unroll
        for (int j = 0; j < 8; ++j) o[j] = (short)f2bf(s[(size_t)j * 512]);
        *(short8v*)(gW1T + (size_t)u * 8) = o;
    }
}

// ============== converter: inputs -> bf16 pre-swizzled, LDS-staged ==============
__global__ __launch_bounds__(256) void convert_inputs(
    const float* __restrict__ text, const float* __restrict__ image,
    unsigned short* __restrict__ textW, unsigned short* __restrict__ imageW)
{
    __shared__ __align__(16) char cbuf[8192];

    const int t = threadIdx.x;
    const int tensor = blockIdx.x >> 10;
    const int rb = blockIdx.x & 1023;
    const float* in = tensor ? image : text;
    unsigned short* outp = tensor ? imageW : textW;

    const int row = t >> 2, cq = t & 3;

    for (int s = 0; s < 8; ++s) {
        const float* src = in + ((size_t)rb * 64 + row) * 512 + s * 64 + cq * 16;
        float4 v0 = ((const float4*)src)[0];
        float4 v1 = ((const float4*)src)[1];
        float4 v2 = ((const float4*)src)[2];
        float4 v3 = ((const float4*)src)[3];
        {
            int oct = 2 * cq;
            uint4 p; p.x = pk2(v0.x, v0.y); p.y = pk2(v0.z, v0.w);
            p.z = pk2(v1.x, v1.y); p.w = pk2(v1.z, v1.w);
            *(uint4*)(cbuf + oct * 1024 + ((row * 16) ^ (oct << 4))) = p;
        }
        {
            int oct = 2 * cq + 1;
            uint4 p; p.x = pk2(v2.x, v2.y); p.y = pk2(v2.z, v2.w);
            p.z = pk2(v3.x, v3.y); p.w = pk2(v3.z, v3.w);
            *(uint4*)(cbuf + oct * 1024 + ((row * 16) ^ (oct << 4))) = p;
        }
        __syncthreads();
        unsigned short* dst = outp + ((size_t)rb * 4096 + s * 512 + t * 2) * 8;
        *(uint4*)dst = *(uint4*)(cbuf + t * 32);
        *(uint4*)(dst + 8) = *(uint4*)(cbuf + t * 32 + 16);
        __syncthreads();
    }
}

// ============== fused main: blocks 0..2047 global path (32 rows each, gs -> out),
//                blocks 2048..10239 head path (per_aspect) ==============
// __launch_bounds__(512,2): empirically hipcc maps (512,4)->64-VGPR cap (spilled),
// (512,2)->128 cap (R5). Branches need <=~100 -> no spills; occupancy still
// LDS-bound at 2 blocks/CU (80KB) and <=128 VGPR sustains 4 waves/SIMD.
__global__ __launch_bounds__(512, 2) void fused_main(
    const unsigned short* __restrict__ textW, const unsigned short* __restrict__ imageW,
    const unsigned short* __restrict__ W1L, const float* __restrict__ b1,
    const float* __restrict__ ln1g, const float* __restrict__ ln1b,
    const unsigned short* __restrict__ W2T, const float* __restrict__ b2,
    const unsigned short* __restrict__ gW1T, const float* __restrict__ gb1,
    const float* __restrict__ glng, const float* __restrict__ glnb,
    const float* __restrict__ gW2, const float* __restrict__ gb2,
    float* __restrict__ out_gs_conflict, float* __restrict__ out_pa)
{
    __shared__ __align__(1024) char smem[79872];

    const int tid = threadIdx.x;
    const int w = tid >> 6, lane = tid & 63, lg = lane >> 4, lc = lane & 15;

    if (blockIdx.x < 2048) {
        // ================= GLOBAL PATH: 32 rows x 512 cols =================
        // LDS: A0@0 (2K) | A1@2048 | B0@4096 (32K) | B1@36864 | sStat@69632 (2K) | sDot@71680 (1K)
        char* gsm = smem;
        const size_t row0 = (size_t)blockIdx.x * 32;
        const int rb = blockIdx.x >> 1;          // 64-row ws block
        const int half = blockIdx.x & 1;         // which 32-row half
        const char* gWb = (const char*)gW1T;
        const char* tWb = (const char*)textW + (size_t)rb * 65536;
        const char* iWb = (const char*)imageW + (size_t)rb * 65536;
        float* sStat = (float*)(gsm + 69632);
        float* sDot  = (float*)(gsm + 71680);

#define STAGE(p_, st_) do { \
    char* bb_ = gsm + 4096 + (p_) * 32768 + w * 4096; \
    const char* bs_ = gWb + (size_t)(st_) * 32768 + w * 4096 + lane * 16; \
    glds16(bs_, bb_); glds16(bs_ + 1024, bb_ + 1024); \
    glds16(bs_ + 2048, bb_ + 2048); glds16(bs_ + 3072, bb_ + 3072); \
    if (w < 2) { \
        int stx_ = (st_) & 15; \
        const char* base_ = ((st_) < 16) ? tWb : iWb; \
        int oct_ = (stx_ & 1) * 4 + 2 * w + (lane >> 5); \
        const char* as_ = base_ + (stx_ >> 1) * 8192 + oct_ * 1024 \
                        + (32 * half + (lane & 31)) * 16; \
        glds16(as_, gsm + (p_) * 2048 + w * 1024); \
    } } while (0)

        STAGE(0, 0);
        __syncthreads();

        f32x4 acc[2][4];
        #pragma unroll
        for (int rt = 0; rt < 2; ++rt)
            #pragma unroll
            for (int nt = 0; nt < 4; ++nt) acc[rt][nt] = (f32x4){0.f, 0.f, 0.f, 0.f};

        #pragma unroll 2
        for (int st = 0; st < 32; ++st) {
            const int cur = st & 1;
            char* bufAc = gsm + cur * 2048;
            char* bufBc = gsm + 4096 + cur * 32768;
            if (st < 31) STAGE(cur ^ 1, st + 1);

            const int ob = (st & 1) * 4;
            short8v af[2];
            #pragma unroll
            for (int rt = 0; rt < 2; ++rt)
                af[rt] = *(const short8v*)(bufAc + lg * 512
                            + (16 * rt + (lc ^ (ob + lg))) * 16);
            #pragma unroll
            for (int nt = 0; nt < 4; ++nt) {
                short8v bfv = *(const short8v*)(bufBc + (4 * w + nt) * 1024 + lane * 16);
                acc[0][nt] = __builtin_amdgcn_mfma_f32_16x16x32_bf16(af[0], bfv, acc[0][nt], 0, 0, 0);
                acc[1][nt] = __builtin_amdgcn_mfma_f32_16x16x32_bf16(af[1], bfv, acc[1][nt], 0, 0, 0);
            }
            __syncthreads();
        }
#undef STAGE

        // ---- + gb1, LN stat partials ----
        #pragma unroll
        for (int nt = 0; nt < 4; ++nt) {
            float bv = gb1[64 * w + 16 * nt + lc];
            #pragma unroll
            for (int rt = 0; rt < 2; ++rt)
                #pragma unroll
                for (int reg = 0; reg < 4; ++reg) acc[rt][nt][reg] += bv;
        }
        #pragma unroll
        for (int rt = 0; rt < 2; ++rt)
            #pragma unroll
            for (int reg = 0; reg < 4; ++reg) {
                float s1 = 0.f, s2 = 0.f;
                #pragma unroll
                for (int nt = 0; nt < 4; ++nt) { float v = acc[rt][nt][reg]; s1 += v; s2 += v * v; }
                #pragma unroll
                for (int off = 1; off < 16; off <<= 1) {
                    s1 += __shfl_xor(s1, off, 64);
                    s2 += __shfl_xor(s2, off, 64);
                }
                if (lc == 0) {
                    int rr = 16 * rt + 4 * lg + reg;
                    sStat[(w * 32 + rr) * 2 + 0] = s1;
                    sStat[(w * 32 + rr) * 2 + 1] = s2;
                }
            }
        __syncthreads();

        float mug[2][4], rsg[2][4];
        #pragma unroll
        for (int rt = 0; rt < 2; ++rt)
            #pragma unroll
            for (int reg = 0; reg < 4; ++reg) {
                int rr = 16 * rt + 4 * lg + reg;
                float s1 = 0.f, s2 = 0.f;
                #pragma unroll
                for (int ww = 0; ww < 8; ++ww) {
                    s1 += sStat[(ww * 32 + rr) * 2 + 0];
                    s2 += sStat[(ww * 32 + rr) * 2 + 1];
                }
                float m = s1 * (1.0f / 512.0f);
                float var = s2 * (1.0f / 512.0f) - m * m;
                mug[rt][reg] = m;
                rsg[rt][reg] = rsqrtf(var + 1e-5f);
            }

        // ---- LN + GELU + dot(gW2) partials ----
        float dp[2][4];
        #pragma unroll
        for (int rt = 0; rt < 2; ++rt)
            #pragma unroll
            for (int reg = 0; reg < 4; ++reg) dp[rt][reg] = 0.f;
        #pragma unroll
        for (int nt = 0; nt < 4; ++nt) {
            int col = 64 * w + 16 * nt + lc;
            float gv = glng[col], bv = glnb[col], wv = gW2[col];
            #pragma unroll
            for (int rt = 0; rt < 2; ++rt)
                #pragma unroll
                for (int reg = 0; reg < 4; ++reg) {
                    float v = (acc[rt][nt][reg] - mug[rt][reg]) * rsg[rt][reg] * gv + bv;
                    dp[rt][reg] += gelu_exact(v) * wv;
                }
        }
        #pragma unroll
        for (int rt = 0; rt < 2; ++rt)
            #pragma unroll
            for (int reg = 0; reg < 4; ++reg) {
                float d = dp[rt][reg];
                #pragma unroll
                for (int off = 1; off < 16; off <<= 1) d += __shfl_xor(d, off, 64);
                if (lc == 0) sDot[w * 32 + 16 * rt + 4 * lg + reg] = d;
            }
        __syncthreads();

        if (tid < 32) {
            int rr = tid;
            float z = gb2[0];
            #pragma unroll
            for (int ww = 0; ww < 8; ++ww) z += sDot[ww * 32 + rr];
            out_gs_conflict[row0 + rr] = 1.0f / (1.0f + expf(-z));
        }
        return;
    }

    // ================= HEAD PATH (proven body, bid shifted) =================
    const int bid = blockIdx.x - 2048;
    const int wr = w >> 1, wc = w & 1;
    const int xr = bid & 7;
    const int q = bid >> 3;
    const int hd = q & 7;
    const int rb = ((q >> 3) << 3) | xr;
    const size_t row0 = (size_t)rb * 64;

    const char* W1base = (const char*)W1L + (size_t)hd * 131072;
    const char* tWb = (const char*)textW + (size_t)rb * 65536 + w * 1024 + lane * 16;
    const char* iWb = (const char*)imageW + (size_t)rb * 65536 + w * 1024 + lane * 16;
    float* sS = (float*)(smem + 65536);
    unsigned short* hb = (unsigned short*)(smem + 67584 + w * 1152);

#define STAGE_A(buf_, s_) do { \
    glds16(tWb + (s_) * 8192, (buf_) + w * 2048); \
    glds16(iWb + (s_) * 8192, (buf_) + w * 2048 + 1024); } while (0)
#define STAGE_B(buf_, s_) do { \
    const char* bs_ = W1base + (s_) * 16384 + w * 2048 + lane * 16; \
    glds16(bs_, (buf_) + w * 2048); \
    glds16(bs_ + 1024, (buf_) + w * 2048 + 1024); } while (0)

    STAGE_A(smem, 0);
    STAGE_B(smem + 32768, 0);
    __syncthreads();

    f32x4 acc[2][4];
    #pragma unroll
    for (int rt = 0; rt < 2; ++rt)
        #pragma unroll
        for (int nt = 0; nt < 4; ++nt) acc[rt][nt] = (f32x4){0.f, 0.f, 0.f, 0.f};

    #pragma unroll
    for (int s = 0; s < 8; ++s) {
        const int cur = s & 1;
        char* bufAc = smem + cur * 16384;
        char* bufBc = smem + 32768 + cur * 16384;
        if (s < 7) {
            STAGE_A(smem + (cur ^ 1) * 16384, s + 1);
            STAGE_B(smem + 32768 + (cur ^ 1) * 16384, s + 1);
        }
        #pragma unroll
        for (int kk = 0; kk < 2; ++kk) {
            const int o = kk * 4 + lg;
            short8v afv[2];
            #pragma unroll
            for (int rt = 0; rt < 2; ++rt) {
                const int row = 32 * wr + 16 * rt + lc;
                afv[rt] = *(const short8v*)(bufAc + o * 2048 + ((row * 16) ^ (o << 4)));
            }
            #pragma unroll
            for (int nt = 0; nt < 4; ++nt) {
                short8v bfv = *(const short8v*)(bufBc + kk * 8192 + (4 * wc + nt) * 1024 + lane * 16);
                acc[0][nt] = __builtin_amdgcn_mfma_f32_16x16x32_bf16(afv[0], bfv, acc[0][nt], 0, 0, 0);
                acc[1][nt] = __builtin_amdgcn_mfma_f32_16x16x32_bf16(afv[1], bfv, acc[1][nt], 0, 0, 0);
            }
        }
        __syncthreads();
    }
#undef STAGE_A
#undef STAGE_B

    #pragma unroll
    for (int nt = 0; nt < 4; ++nt) {
        float bv = b1[hd * 128 + 64 * wc + 16 * nt + lc];
        #pragma unroll
        for (int rt = 0; rt < 2; ++rt)
            #pragma unroll
            for (int reg = 0; reg < 4; ++reg) acc[rt][nt][reg] += bv;
    }
    #pragma unroll
    for (int rt = 0; rt < 2; ++rt)
        #pragma unroll
        for (int reg = 0; reg < 4; ++reg) {
            float s1 = 0.f, s2 = 0.f;
            #pragma unroll
            for (int nt = 0; nt < 4; ++nt) { float v = acc[rt][nt][reg]; s1 += v; s2 += v * v; }
            #pragma unroll
            for (int off = 1; off < 16; off <<= 1) {
                s1 += __shfl_xor(s1, off, 64);
                s2 += __shfl_xor(s2, off, 64);
            }
            if (lc == 0) {
                int row = 32 * wr + 16 * rt + 4 * lg + reg;
                sS[(wc * 128 + row) * 2 + 0] = s1;
                sS[(wc * 128 + row) * 2 + 1] = s2;
            }
        }
    __syncthreads();

    float mu[2][4], rsig[2][4];
    #pragma unroll
    for (int rt = 0; rt < 2; ++rt)
        #pragma unroll
        for (int reg = 0; reg < 4; ++reg) {
            int row = 32 * wr + 16 * rt + 4 * lg + reg;
            float s1 = sS[row * 2 + 0] + sS[(128 + row) * 2 + 0];
            float s2 = sS[row * 2 + 1] + sS[(128 + row) * 2 + 1];
            float m = s1 * (1.0f / 128.0f);
            float var = s2 * (1.0f / 128.0f) - m * m;
            mu[rt][reg] = m;
            rsig[rt][reg] = rsqrtf(var + 1e-5f);
        }
    #pragma unroll
    for (int nt = 0; nt < 4; ++nt) {
        int col = 64 * wc + 16 * nt + lc;
        float gv = ln1g[hd * 128 + col];
        float bv = ln1b[hd * 128 + col];
        #pragma unroll
        for (int rt = 0; rt < 2; ++rt)
            #pragma unroll
            for (int reg = 0; reg < 4; ++reg) {
                float v = (acc[rt][nt][reg] - mu[rt][reg]) * rsig[rt][reg] * gv + bv;
                acc[rt][nt][reg] = gelu_exact(v);
            }
    }

    const char* W2b = (const char*)W2T + (size_t)hd * 16384;
    #pragma unroll
    for (int rt = 0; rt < 2; ++rt) {
        f32x4 acc2[4];
        #pragma unroll
        for (int nt2 = 0; nt2 < 4; ++nt2) acc2[nt2] = (f32x4){0.f, 0.f, 0.f, 0.f};

        #pragma unroll
        for (int kk2 = 0; kk2 < 2; ++kk2) {
            #pragma unroll
            for (int ntl = 0; ntl < 2; ++ntl) {
                const int nt = 2 * kk2 + ntl;
                const int kk = 16 * ntl + lc;
                #pragma unroll
                for (int reg = 0; reg < 4; ++reg)
                    hb[(4 * lg + reg) * 36 + kk] = f2bf(acc[rt][nt][reg]);
            }
            short8v af2 = *(const short8v*)((const char*)hb + lc * 72 + 16 * lg);
            const char* wb = W2b + (2 * wc + kk2) * 4096 + lane * 16;
            #pragma unroll
            for (int nt2 = 0; nt2 < 4; ++nt2) {
                short8v w2f = *(const short8v*)(wb + nt2 * 1024);
                acc2[nt2] = __builtin_amdgcn_mfma_f32_16x16x32_bf16(af2, w2f, acc2[nt2], 0, 0, 0);
            }
        }
        if (wc == 0) {
            #pragma unroll
            for (int nt2 = 0; nt2 < 4; ++nt2) {
                float bv = b2[hd * 64 + 16 * nt2 + lc];
                #pragma unroll
                for (int reg = 0; reg < 4; ++reg) {
                    int row = 32 * wr + 16 * rt + 4 * lg + reg;
                    int col = 16 * nt2 + lc;
                    *(float*)(smem + row * 256 + ((col * 4) ^ ((row & 7) << 4))) = acc2[nt2][reg] + bv;
                }
            }
        }
        __syncthreads();
        if (wc == 1) {
            #pragma unroll
            for (int nt2 = 0; nt2 < 4; ++nt2)
                #pragma unroll
                for (int reg = 0; reg < 4; ++reg) {
                    int row = 32 * wr + 16 * rt + 4 * lg + reg;
                    int col = 16 * nt2 + lc;
                    float* p = (float*)(smem + row * 256 + ((col * 4) ^ ((row & 7) << 4)));
                    *p += acc2[nt2][reg];
                }
        }
        __syncthreads();
    }

    if (w < 4) {
        int r = 16 * w + lc;
        int sw = (r & 7) << 4;
        float nt_ = 0.f, ni_ = 0.f, pr = 0.f;
        #pragma unroll
        for (int q2 = 0; q2 < 4; ++q2) {
            int c16 = 2 * lg + (q2 & 1) + (q2 >> 1) * 8;
            float4 a = *(const float4*)(smem + r * 256 + ((c16 * 16) ^ sw));
            float4 b = *(const float4*)(smem + (r + 64) * 256 + ((c16 * 16) ^ sw));
            nt_ += a.x * a.x + a.y * a.y + a.z * a.z + a.w * a.w;
            ni_ += b.x * b.x + b.y * b.y + b.z * b.z + b.w * b.w;
            pr  += a.x * b.x + a.y * b.y + a.z * b.z + a.w * b.w;
        }
        nt_ += __shfl_xor(nt_, 16, 64); ni_ += __shfl_xor(ni_, 16, 64); pr += __shfl_xor(pr, 16, 64);
        nt_ += __shfl_xor(nt_, 32, 64); ni_ += __shfl_xor(ni_, 32, 64); pr += __shfl_xor(pr, 32, 64);
        if (lg == 0) {
            float denom = fmaxf(sqrtf(nt_), 1e-12f) * fmaxf(sqrtf(ni_), 1e-12f);
            out_pa[(row0 + r) * 8 + hd] = pr / denom;
        }
    }
}

// ============== finalize: conflict = clip(1 - 0.7*softmax(aw)@pa - 0.3*gs) ==============
__global__ __launch_bounds__(256) void finalize(
    const float* __restrict__ aw, const float* __restrict__ pa,
    float* __restrict__ out_conflict)
{
    int r = blockIdx.x * 256 + threadIdx.x;
    float wv[8], mx = -1e30f;
    #pragma unroll
    for (int i = 0; i < 8; ++i) { wv[i] = aw[i]; mx = fmaxf(mx, wv[i]); }
    float sum = 0.f;
    #pragma unroll
    for (int i = 0; i < 8; ++i) { wv[i] = __expf(wv[i] - mx); sum += wv[i]; }
    float inv = __builtin_amdgcn_rcpf(sum);
    const float* par = pa + (size_t)r * 8;
    float4 p0 = ((const float4*)par)[0];
    float4 p1 = ((const float4*)par)[1];
    float wsim = p0.x * wv[0] + p0.y * wv[1] + p0.z * wv[2] + p0.w * wv[3]
               + p1.x * wv[4] + p1.y * wv[5] + p1.z * wv[6] + p1.w * wv[7];
    wsim *= inv;
    float gs = out_conflict[r];
    float conf = 1.0f - (0.7f * wsim + 0.3f * gs);
    out_conflict[r] = fminf(fmaxf(conf, 0.0f), 1.0f);
}

extern "C" void kernel_launch(void* const* d_in, const int* in_sizes, int n_in,
                              void* d_out, int out_size, void* d_ws, size_t ws_size,
                              hipStream_t stream) {
    const float* text  = (const float*)d_in[0];
    const float* image = (const float*)d_in[1];
    const float* W1    = (const float*)d_in[2];
    const float* b1    = (const float*)d_in[3];
    const float* ln1g  = (const float*)d_in[4];
    const float* ln1b  = (const float*)d_in[5];
    const float* W2    = (const float*)d_in[6];
    const float* b2    = (const float*)d_in[7];
    const float* aw    = (const float*)d_in[8];
    const float* gW1   = (const float*)d_in[9];
    const float* gb1   = (const float*)d_in[10];
    const float* glng  = (const float*)d_in[11];
    const float* glnb  = (const float*)d_in[12];
    const float* gW2   = (const float*)d_in[13];
    const float* gb2   = (const float*)d_in[14];

    float* out = (float*)d_out;
    float* out_pa = out + B_TOTAL;

    unsigned short* textW  = (unsigned short*)d_ws;                           // 64MB
    unsigned short* imageW = (unsigned short*)((char*)d_ws + 67108864);       // 64MB
    unsigned short* W1L    = (unsigned short*)((char*)d_ws + 134217728);      // 1MB
    unsigned short* W2T    = (unsigned short*)((char*)d_ws + 135266304);      // 128KB
    unsigned short* gW1T   = (unsigned short*)((char*)d_ws + 135397376);      // 1MB

    convert_weights<<<544, 256, 0, stream>>>(W1, W2, gW1, W1L, W2T, gW1T);
    convert_inputs<<<2048, 256, 0, stream>>>(text, image, textW, imageW);
    fused_main<<<10240, 512, 0, stream>>>(textW, imageW, W1L, b1, ln1g, ln1b, W2T, b2,
                                          gW1T, gb1, glng, glnb, gW2, gb2,
                                          out, out_pa);
    finalize<<<256, 256, 0, stream>>>(aw, out_pa, out);
}

// Round 18
// 488.925 us; speedup vs baseline: 1.3263x; 1.3263x over previous
//
#include <hip/hip_runtime.h>
#include <hip/hip_bf16.h>
#include <math.h>

#define B_TOTAL 65536

typedef __attribute__((ext_vector_type(8))) short short8v;   // 8 bf16 (4 VGPRs)
typedef __attribute__((ext_vector_type(4))) float f32x4;

__device__ __forceinline__ unsigned short f2bf(float f) {
    union { float f; unsigned u; } v; v.f = f;
    unsigned r = v.u + 0x7FFF + ((v.u >> 16) & 1);   // RNE
    return (unsigned short)(r >> 16);
}

__device__ __forceinline__ unsigned pk2(float a, float b) {
    float2 t; t.x = a; t.y = b;
    __hip_bfloat162 h = __float22bfloat162_rn(t);    // v_cvt_pk_bf16_f32
    union { __hip_bfloat162 h; unsigned u; } c; c.h = h;
    return c.u;
}

// Abramowitz-Stegun 7.1.26 with v_rcp_f32 (rcp rel-err ~1e-7 << formula err 1.5e-7)
__device__ __forceinline__ float erf_fast(float x) {
    float ax = fabsf(x);
    float t = __builtin_amdgcn_rcpf(fmaf(0.3275911f, ax, 1.0f));
    float y = t * (0.254829592f + t * (-0.284496736f + t * (1.421413741f
              + t * (-1.453152027f + t * 1.061405429f))));
    float r = 1.0f - y * __expf(-ax * ax);
    return copysignf(r, x);
}

__device__ __forceinline__ float gelu_exact(float x) {
    return 0.5f * x * (1.0f + erf_fast(x * 0.70710678118654752440f));
}

__device__ __forceinline__ void glds16(const void* g, void* l) {
    __builtin_amdgcn_global_load_lds(
        (const __attribute__((address_space(1))) unsigned int*)g,
        (__attribute__((address_space(3))) unsigned int*)l, 16, 0, 0);
}

// ============== converter: weights -> fragment-linear bf16 in ws ==============
__global__ void convert_weights(const float* __restrict__ W1, const float* __restrict__ W2,
                                const float* __restrict__ gW1,
                                unsigned short* __restrict__ W1L, unsigned short* __restrict__ W2T,
                                unsigned short* __restrict__ gW1T)
{
    int t = blockIdx.x * 256 + threadIdx.x;
    if (t < 65536) {
        int l = t & 63, nt = (t >> 6) & 7, step = (t >> 9) & 15, hd = t >> 13;
        int n = nt * 16 + (l & 15);
        int k = step * 32 + 8 * (l >> 4);
        const float* s = W1 + (size_t)hd * 65536 + (size_t)k * 128 + n;
        short8v o;
        #pragma unroll
        for (int j = 0; j < 8; ++j) o[j] = (short)f2bf(s[(size_t)j * 128]);
        *(short8v*)(W1L + (size_t)t * 8) = o;
    } else if (t < 65536 + 8192) {
        int u = t - 65536;
        int l = u & 63, nt = (u >> 6) & 3, kb = (u >> 8) & 3, hd = u >> 10;
        int m = 16 * nt + (l & 15);
        int k = 32 * kb + 8 * (l >> 4);
        const float* s = W2 + (size_t)hd * 8192 + (size_t)k * 64 + m;
        short8v o;
        #pragma unroll
        for (int j = 0; j < 8; ++j) o[j] = (short)f2bf(s[(size_t)j * 64]);
        *(short8v*)(W2T + (size_t)u * 8) = o;
    } else if (t < 65536 + 8192 + 65536) {
        int u = t - 73728;
        int l = u & 63, nt = (u >> 6) & 31, s0 = u >> 11;
        int n = 16 * nt + (l & 15);
        int k = 32 * s0 + 8 * (l >> 4);
        const float* s = gW1 + (size_t)k * 512 + n;
        short8v o;
        #pragma unroll
        for (int j = 0; j < 8; ++j) o[j] = (short)f2bf(s[(size_t)j * 512]);
        *(short8v*)(gW1T + (size_t)u * 8) = o;
    }
}

// ============== converter: inputs -> bf16 pre-swizzled, LDS-staged ==============
__global__ __launch_bounds__(256) void convert_inputs(
    const float* __restrict__ text, const float* __restrict__ image,
    unsigned short* __restrict__ textW, unsigned short* __restrict__ imageW)
{
    __shared__ __align__(16) char cbuf[8192];

    const int t = threadIdx.x;
    const int tensor = blockIdx.x >> 10;
    const int rb = blockIdx.x & 1023;
    const float* in = tensor ? image : text;
    unsigned short* outp = tensor ? imageW : textW;

    const int row = t >> 2, cq = t & 3;

    for (int s = 0; s < 8; ++s) {
        const float* src = in + ((size_t)rb * 64 + row) * 512 + s * 64 + cq * 16;
        float4 v0 = ((const float4*)src)[0];
        float4 v1 = ((const float4*)src)[1];
        float4 v2 = ((const float4*)src)[2];
        float4 v3 = ((const float4*)src)[3];
        {
            int oct = 2 * cq;
            uint4 p; p.x = pk2(v0.x, v0.y); p.y = pk2(v0.z, v0.w);
            p.z = pk2(v1.x, v1.y); p.w = pk2(v1.z, v1.w);
            *(uint4*)(cbuf + oct * 1024 + ((row * 16) ^ (oct << 4))) = p;
        }
        {
            int oct = 2 * cq + 1;
            uint4 p; p.x = pk2(v2.x, v2.y); p.y = pk2(v2.z, v2.w);
            p.z = pk2(v3.x, v3.y); p.w = pk2(v3.z, v3.w);
            *(uint4*)(cbuf + oct * 1024 + ((row * 16) ^ (oct << 4))) = p;
        }
        __syncthreads();
        unsigned short* dst = outp + ((size_t)rb * 4096 + s * 512 + t * 2) * 8;
        *(uint4*)dst = *(uint4*)(cbuf + t * 32);
        *(uint4*)(dst + 8) = *(uint4*)(cbuf + t * 32 + 16);
        __syncthreads();
    }
}

// ============== fused main: blocks 0..2047 global path (32 rows each, gs -> out),
//                blocks 2048..10239 head path (per_aspect) ==============
// (512,4) -> 64-VGPR cap (2 blocks/CU). Global epilogue keeps register peak <=64
// by dumping acc through a 64KB LDS oTile (R8 pattern) instead of holding
// acc+stats+dot live simultaneously (R16's residual 158MB spill source).
__global__ __launch_bounds__(512, 4) void fused_main(
    const unsigned short* __restrict__ textW, const unsigned short* __restrict__ imageW,
    const unsigned short* __restrict__ W1L, const float* __restrict__ b1,
    const float* __restrict__ ln1g, const float* __restrict__ ln1b,
    const unsigned short* __restrict__ W2T, const float* __restrict__ b2,
    const unsigned short* __restrict__ gW1T, const float* __restrict__ gb1,
    const float* __restrict__ glng, const float* __restrict__ glnb,
    const float* __restrict__ gW2, const float* __restrict__ gb2,
    float* __restrict__ out_gs_conflict, float* __restrict__ out_pa)
{
    __shared__ __align__(1024) char smem[79872];

    const int tid = threadIdx.x;
    const int w = tid >> 6, lane = tid & 63, lg = lane >> 4, lc = lane & 15;

    if (blockIdx.x < 2048) {
        // ================= GLOBAL PATH: 32 rows x 512 cols =================
        // K-loop LDS: A0@0 (2K) | A1@2048 | B0@4096 (32K) | B1@36864
        // sStat@69632 (2K) | sDot@71680 (128B); epilogue oTile [32][512] f32 @0..64K
        char* gsm = smem;
        const size_t row0 = (size_t)blockIdx.x * 32;
        const int rb = blockIdx.x >> 1;
        const int half = blockIdx.x & 1;
        const char* gWb = (const char*)gW1T;
        const char* tWb = (const char*)textW + (size_t)rb * 65536;
        const char* iWb = (const char*)imageW + (size_t)rb * 65536;
        float* sStat = (float*)(gsm + 69632);
        float* sDot  = (float*)(gsm + 71680);

#define STAGE(p_, st_) do { \
    char* bb_ = gsm + 4096 + (p_) * 32768 + w * 4096; \
    const char* bs_ = gWb + (size_t)(st_) * 32768 + w * 4096 + lane * 16; \
    glds16(bs_, bb_); glds16(bs_ + 1024, bb_ + 1024); \
    glds16(bs_ + 2048, bb_ + 2048); glds16(bs_ + 3072, bb_ + 3072); \
    if (w < 2) { \
        int stx_ = (st_) & 15; \
        const char* base_ = ((st_) < 16) ? tWb : iWb; \
        int oct_ = (stx_ & 1) * 4 + 2 * w + (lane >> 5); \
        const char* as_ = base_ + (stx_ >> 1) * 8192 + oct_ * 1024 \
                        + (32 * half + (lane & 31)) * 16; \
        glds16(as_, gsm + (p_) * 2048 + w * 1024); \
    } } while (0)

        STAGE(0, 0);
        __syncthreads();

        f32x4 acc[2][4];
        #pragma unroll
        for (int rt = 0; rt < 2; ++rt)
            #pragma unroll
            for (int nt = 0; nt < 4; ++nt) acc[rt][nt] = (f32x4){0.f, 0.f, 0.f, 0.f};

        #pragma unroll 2
        for (int st = 0; st < 32; ++st) {
            const int cur = st & 1;
            char* bufAc = gsm + cur * 2048;
            char* bufBc = gsm + 4096 + cur * 32768;
            if (st < 31) STAGE(cur ^ 1, st + 1);

            const int ob = (st & 1) * 4;
            short8v af[2];
            #pragma unroll
            for (int rt = 0; rt < 2; ++rt)
                af[rt] = *(const short8v*)(bufAc + lg * 512
                            + (16 * rt + (lc ^ (ob + lg))) * 16);
            #pragma unroll
            for (int nt = 0; nt < 4; ++nt) {
                short8v bfv = *(const short8v*)(bufBc + (4 * w + nt) * 1024 + lane * 16);
                acc[0][nt] = __builtin_amdgcn_mfma_f32_16x16x32_bf16(af[0], bfv, acc[0][nt], 0, 0, 0);
                acc[1][nt] = __builtin_amdgcn_mfma_f32_16x16x32_bf16(af[1], bfv, acc[1][nt], 0, 0, 0);
            }
            __syncthreads();
        }
#undef STAGE

        // ---- + gb1, LN stat partials (from regs), then dump acc -> oTile ----
        #pragma unroll
        for (int nt = 0; nt < 4; ++nt) {
            float bv = gb1[64 * w + 16 * nt + lc];
            #pragma unroll
            for (int rt = 0; rt < 2; ++rt)
                #pragma unroll
                for (int reg = 0; reg < 4; ++reg) acc[rt][nt][reg] += bv;
        }
        #pragma unroll
        for (int rt = 0; rt < 2; ++rt)
            #pragma unroll
            for (int reg = 0; reg < 4; ++reg) {
                float s1 = 0.f, s2 = 0.f;
                #pragma unroll
                for (int nt = 0; nt < 4; ++nt) { float v = acc[rt][nt][reg]; s1 += v; s2 += v * v; }
                #pragma unroll
                for (int off = 1; off < 16; off <<= 1) {
                    s1 += __shfl_xor(s1, off, 64);
                    s2 += __shfl_xor(s2, off, 64);
                }
                if (lc == 0) {
                    int rr = 16 * rt + 4 * lg + reg;
                    sStat[(w * 32 + rr) * 2 + 0] = s1;
                    sStat[(w * 32 + rr) * 2 + 1] = s2;
                }
            }
        // dump (A/B buffers retired after final loop barrier; writes only -> no barrier needed)
        #pragma unroll
        for (int rt = 0; rt < 2; ++rt)
            #pragma unroll
            for (int nt = 0; nt < 4; ++nt)
                #pragma unroll
                for (int reg = 0; reg < 4; ++reg) {
                    int row = 16 * rt + 4 * lg + reg;
                    int col = 64 * w + 16 * nt + lc;
                    *(float*)(gsm + row * 2048 + ((col * 4) ^ ((row & 7) << 4))) = acc[rt][nt][reg];
                }
        __syncthreads();

        // ---- low-register epilogue: thread = (row = tid>>4, part = tid&15) ----
        {
            const int row = tid >> 4, part = tid & 15;
            float s1 = 0.f, s2 = 0.f;
            #pragma unroll
            for (int ww = 0; ww < 8; ++ww) {
                s1 += sStat[(ww * 32 + row) * 2 + 0];
                s2 += sStat[(ww * 32 + row) * 2 + 1];
            }
            float mu = s1 * (1.0f / 512.0f);
            float var = s2 * (1.0f / 512.0f) - mu * mu;
            float rsig = rsqrtf(var + 1e-5f);
            float dp = 0.f;
            #pragma unroll 4
            for (int j = 0; j < 32; ++j) {
                int col = part + 16 * j;
                float v = *(const float*)(gsm + row * 2048 + ((col * 4) ^ ((row & 7) << 4)));
                v = (v - mu) * rsig * glng[col] + glnb[col];
                dp += gelu_exact(v) * gW2[col];
            }
            #pragma unroll
            for (int off = 1; off < 16; off <<= 1) dp += __shfl_xor(dp, off, 64);
            if (part == 0) sDot[row] = dp;
        }
        __syncthreads();

        if (tid < 32) {
            float z = sDot[tid] + gb2[0];
            out_gs_conflict[row0 + tid] = 1.0f / (1.0f + expf(-z));
        }
        return;
    }

    // ================= HEAD PATH (proven body, bid shifted) =================
    const int bid = blockIdx.x - 2048;
    const int wr = w >> 1, wc = w & 1;
    const int xr = bid & 7;
    const int q = bid >> 3;
    const int hd = q & 7;
    const int rb = ((q >> 3) << 3) | xr;
    const size_t row0 = (size_t)rb * 64;

    const char* W1base = (const char*)W1L + (size_t)hd * 131072;
    const char* tWb = (const char*)textW + (size_t)rb * 65536 + w * 1024 + lane * 16;
    const char* iWb = (const char*)imageW + (size_t)rb * 65536 + w * 1024 + lane * 16;
    float* sS = (float*)(smem + 65536);
    unsigned short* hb = (unsigned short*)(smem + 67584 + w * 1152);

#define STAGE_A(buf_, s_) do { \
    glds16(tWb + (s_) * 8192, (buf_) + w * 2048); \
    glds16(iWb + (s_) * 8192, (buf_) + w * 2048 + 1024); } while (0)
#define STAGE_B(buf_, s_) do { \
    const char* bs_ = W1base + (s_) * 16384 + w * 2048 + lane * 16; \
    glds16(bs_, (buf_) + w * 2048); \
    glds16(bs_ + 1024, (buf_) + w * 2048 + 1024); } while (0)

    STAGE_A(smem, 0);
    STAGE_B(smem + 32768, 0);
    __syncthreads();

    f32x4 acc[2][4];
    #pragma unroll
    for (int rt = 0; rt < 2; ++rt)
        #pragma unroll
        for (int nt = 0; nt < 4; ++nt) acc[rt][nt] = (f32x4){0.f, 0.f, 0.f, 0.f};

    #pragma unroll
    for (int s = 0; s < 8; ++s) {
        const int cur = s & 1;
        char* bufAc = smem + cur * 16384;
        char* bufBc = smem + 32768 + cur * 16384;
        if (s < 7) {
            STAGE_A(smem + (cur ^ 1) * 16384, s + 1);
            STAGE_B(smem + 32768 + (cur ^ 1) * 16384, s + 1);
        }
        #pragma unroll
        for (int kk = 0; kk < 2; ++kk) {
            const int o = kk * 4 + lg;
            short8v afv[2];
            #pragma unroll
            for (int rt = 0; rt < 2; ++rt) {
                const int row = 32 * wr + 16 * rt + lc;
                afv[rt] = *(const short8v*)(bufAc + o * 2048 + ((row * 16) ^ (o << 4)));
            }
            #pragma unroll
            for (int nt = 0; nt < 4; ++nt) {
                short8v bfv = *(const short8v*)(bufBc + kk * 8192 + (4 * wc + nt) * 1024 + lane * 16);
                acc[0][nt] = __builtin_amdgcn_mfma_f32_16x16x32_bf16(afv[0], bfv, acc[0][nt], 0, 0, 0);
                acc[1][nt] = __builtin_amdgcn_mfma_f32_16x16x32_bf16(afv[1], bfv, acc[1][nt], 0, 0, 0);
            }
        }
        __syncthreads();
    }
#undef STAGE_A
#undef STAGE_B

    #pragma unroll
    for (int nt = 0; nt < 4; ++nt) {
        float bv = b1[hd * 128 + 64 * wc + 16 * nt + lc];
        #pragma unroll
        for (int rt = 0; rt < 2; ++rt)
            #pragma unroll
            for (int reg = 0; reg < 4; ++reg) acc[rt][nt][reg] += bv;
    }
    #pragma unroll
    for (int rt = 0; rt < 2; ++rt)
        #pragma unroll
        for (int reg = 0; reg < 4; ++reg) {
            float s1 = 0.f, s2 = 0.f;
            #pragma unroll
            for (int nt = 0; nt < 4; ++nt) { float v = acc[rt][nt][reg]; s1 += v; s2 += v * v; }
            #pragma unroll
            for (int off = 1; off < 16; off <<= 1) {
                s1 += __shfl_xor(s1, off, 64);
                s2 += __shfl_xor(s2, off, 64);
            }
            if (lc == 0) {
                int row = 32 * wr + 16 * rt + 4 * lg + reg;
                sS[(wc * 128 + row) * 2 + 0] = s1;
                sS[(wc * 128 + row) * 2 + 1] = s2;
            }
        }
    __syncthreads();

    float mu[2][4], rsig[2][4];
    #pragma unroll
    for (int rt = 0; rt < 2; ++rt)
        #pragma unroll
        for (int reg = 0; reg < 4; ++reg) {
            int row = 32 * wr + 16 * rt + 4 * lg + reg;
            float s1 = sS[row * 2 + 0] + sS[(128 + row) * 2 + 0];
            float s2 = sS[row * 2 + 1] + sS[(128 + row) * 2 + 1];
            float m = s1 * (1.0f / 128.0f);
            float var = s2 * (1.0f / 128.0f) - m * m;
            mu[rt][reg] = m;
            rsig[rt][reg] = rsqrtf(var + 1e-5f);
        }
    #pragma unroll
    for (int nt = 0; nt < 4; ++nt) {
        int col = 64 * wc + 16 * nt + lc;
        float gv = ln1g[hd * 128 + col];
        float bv = ln1b[hd * 128 + col];
        #pragma unroll
        for (int rt = 0; rt < 2; ++rt)
            #pragma unroll
            for (int reg = 0; reg < 4; ++reg) {
                float v = (acc[rt][nt][reg] - mu[rt][reg]) * rsig[rt][reg] * gv + bv;
                acc[rt][nt][reg] = gelu_exact(v);
            }
    }

    const char* W2b = (const char*)W2T + (size_t)hd * 16384;
    #pragma unroll
    for (int rt = 0; rt < 2; ++rt) {
        f32x4 acc2[4];
        #pragma unroll
        for (int nt2 = 0; nt2 < 4; ++nt2) acc2[nt2] = (f32x4){0.f, 0.f, 0.f, 0.f};

        #pragma unroll
        for (int kk2 = 0; kk2 < 2; ++kk2) {
            #pragma unroll
            for (int ntl = 0; ntl < 2; ++ntl) {
                const int nt = 2 * kk2 + ntl;
                const int kk = 16 * ntl + lc;
                #pragma unroll
                for (int reg = 0; reg < 4; ++reg)
                    hb[(4 * lg + reg) * 36 + kk] = f2bf(acc[rt][nt][reg]);
            }
            short8v af2 = *(const short8v*)((const char*)hb + lc * 72 + 16 * lg);
            const char* wb = W2b + (2 * wc + kk2) * 4096 + lane * 16;
            #pragma unroll
            for (int nt2 = 0; nt2 < 4; ++nt2) {
                short8v w2f = *(const short8v*)(wb + nt2 * 1024);
                acc2[nt2] = __builtin_amdgcn_mfma_f32_16x16x32_bf16(af2, w2f, acc2[nt2], 0, 0, 0);
            }
        }
        if (wc == 0) {
            #pragma unroll
            for (int nt2 = 0; nt2 < 4; ++nt2) {
                float bv = b2[hd * 64 + 16 * nt2 + lc];
                #pragma unroll
                for (int reg = 0; reg < 4; ++reg) {
                    int row = 32 * wr + 16 * rt + 4 * lg + reg;
                    int col = 16 * nt2 + lc;
                    *(float*)(smem + row * 256 + ((col * 4) ^ ((row & 7) << 4))) = acc2[nt2][reg] + bv;
                }
            }
        }
        __syncthreads();
        if (wc == 1) {
            #pragma unroll
            for (int nt2 = 0; nt2 < 4; ++nt2)
                #pragma unroll
                for (int reg = 0; reg < 4; ++reg) {
                    int row = 32 * wr + 16 * rt + 4 * lg + reg;
                    int col = 16 * nt2 + lc;
                    float* p = (float*)(smem + row * 256 + ((col * 4) ^ ((row & 7) << 4)));
                    *p += acc2[nt2][reg];
                }
        }
        __syncthreads();
    }

    if (w < 4) {
        int r = 16 * w + lc;
        int sw = (r & 7) << 4;
        float nt_ = 0.f, ni_ = 0.f, pr = 0.f;
        #pragma unroll
        for (int q2 = 0; q2 < 4; ++q2) {
            int c16 = 2 * lg + (q2 & 1) + (q2 >> 1) * 8;
            float4 a = *(const float4*)(smem + r * 256 + ((c16 * 16) ^ sw));
            float4 b = *(const float4*)(smem + (r + 64) * 256 + ((c16 * 16) ^ sw));
            nt_ += a.x * a.x + a.y * a.y + a.z * a.z + a.w * a.w;
            ni_ += b.x * b.x + b.y * b.y + b.z * b.z + b.w * b.w;
            pr  += a.x * b.x + a.y * b.y + a.z * b.z + a.w * b.w;
        }
        nt_ += __shfl_xor(nt_, 16, 64); ni_ += __shfl_xor(ni_, 16, 64); pr += __shfl_xor(pr, 16, 64);
        nt_ += __shfl_xor(nt_, 32, 64); ni_ += __shfl_xor(ni_, 32, 64); pr += __shfl_xor(pr, 32, 64);
        if (lg == 0) {
            float denom = fmaxf(sqrtf(nt_), 1e-12f) * fmaxf(sqrtf(ni_), 1e-12f);
            out_pa[(row0 + r) * 8 + hd] = pr / denom;
        }
    }
}

// ============== finalize: conflict = clip(1 - 0.7*softmax(aw)@pa - 0.3*gs) ==============
__global__ __launch_bounds__(256) void finalize(
    const float* __restrict__ aw, const float* __restrict__ pa,
    float* __restrict__ out_conflict)
{
    int r = blockIdx.x * 256 + threadIdx.x;
    float wv[8], mx = -1e30f;
    #pragma unroll
    for (int i = 0; i < 8; ++i) { wv[i] = aw[i]; mx = fmaxf(mx, wv[i]); }
    float sum = 0.f;
    #pragma unroll
    for (int i = 0; i < 8; ++i) { wv[i] = __expf(wv[i] - mx); sum += wv[i]; }
    float inv = __builtin_amdgcn_rcpf(sum);
    const float* par = pa + (size_t)r * 8;
    float4 p0 = ((const float4*)par)[0];
    float4 p1 = ((const float4*)par)[1];
    float wsim = p0.x * wv[0] + p0.y * wv[1] + p0.z * wv[2] + p0.w * wv[3]
               + p1.x * wv[4] + p1.y * wv[5] + p1.z * wv[6] + p1.w * wv[7];
    wsim *= inv;
    float gs = out_conflict[r];
    float conf = 1.0f - (0.7f * wsim + 0.3f * gs);
    out_conflict[r] = fminf(fmaxf(conf, 0.0f), 1.0f);
}

extern "C" void kernel_launch(void* const* d_in, const int* in_sizes, int n_in,
                              void* d_out, int out_size, void* d_ws, size_t ws_size,
                              hipStream_t stream) {
    const float* text  = (const float*)d_in[0];
    const float* image = (const float*)d_in[1];
    const float* W1    = (const float*)d_in[2];
    const float* b1    = (const float*)d_in[3];
    const float* ln1g  = (const float*)d_in[4];
    const float* ln1b  = (const float*)d_in[5];
    const float* W2    = (const float*)d_in[6];
    const float* b2    = (const float*)d_in[7];
    const float* aw    = (const float*)d_in[8];
    const float* gW1   = (const float*)d_in[9];
    const float* gb1   = (const float*)d_in[10];
    const float* glng  = (const float*)d_in[11];
    const float* glnb  = (const float*)d_in[12];
    const float* gW2   = (const float*)d_in[13];
    const float* gb2   = (const float*)d_in[14];

    float* out = (float*)d_out;
    float* out_pa = out + B_TOTAL;

    unsigned short* textW  = (unsigned short*)d_ws;                           // 64MB
    unsigned short* imageW = (unsigned short*)((char*)d_ws + 67108864);       // 64MB
    unsigned short* W1L    = (unsigned short*)((char*)d_ws + 134217728);      // 1MB
    unsigned short* W2T    = (unsigned short*)((char*)d_ws + 135266304);      // 128KB
    unsigned short* gW1T   = (unsigned short*)((char*)d_ws + 135397376);      // 1MB

    convert_weights<<<544, 256, 0, stream>>>(W1, W2, gW1, W1L, W2T, gW1T);
    convert_inputs<<<2048, 256, 0, stream>>>(text, image, textW, imageW);
    fused_main<<<10240, 512, 0, stream>>>(textW, imageW, W1L, b1, ln1g, ln1b, W2T, b2,
                                          gW1T, gb1, glng, glnb, gW2, gb2,
                                          out, out_pa);
    finalize<<<256, 256, 0, stream>>>(aw, out_pa, out);
}

// Round 19
// 481.083 us; speedup vs baseline: 1.3480x; 1.0163x over previous
//
#include <hip/hip_runtime.h>
#include <hip/hip_bf16.h>
#include <math.h>

#define B_TOTAL 65536

typedef __attribute__((ext_vector_type(8))) short short8v;   // 8 bf16 (4 VGPRs)
typedef __attribute__((ext_vector_type(4))) float f32x4;

__device__ __forceinline__ unsigned short f2bf(float f) {
    union { float f; unsigned u; } v; v.f = f;
    unsigned r = v.u + 0x7FFF + ((v.u >> 16) & 1);   // RNE
    return (unsigned short)(r >> 16);
}

__device__ __forceinline__ unsigned pk2(float a, float b) {
    float2 t; t.x = a; t.y = b;
    __hip_bfloat162 h = __float22bfloat162_rn(t);    // v_cvt_pk_bf16_f32
    union { __hip_bfloat162 h; unsigned u; } c; c.h = h;
    return c.u;
}

// Abramowitz-Stegun 7.1.26 with v_rcp_f32 (rcp rel-err ~1e-7 << formula err 1.5e-7)
__device__ __forceinline__ float erf_fast(float x) {
    float ax = fabsf(x);
    float t = __builtin_amdgcn_rcpf(fmaf(0.3275911f, ax, 1.0f));
    float y = t * (0.254829592f + t * (-0.284496736f + t * (1.421413741f
              + t * (-1.453152027f + t * 1.061405429f))));
    float r = 1.0f - y * __expf(-ax * ax);
    return copysignf(r, x);
}

__device__ __forceinline__ float gelu_exact(float x) {
    return 0.5f * x * (1.0f + erf_fast(x * 0.70710678118654752440f));
}

__device__ __forceinline__ void glds16(const void* g, void* l) {
    __builtin_amdgcn_global_load_lds(
        (const __attribute__((address_space(1))) unsigned int*)g,
        (__attribute__((address_space(3))) unsigned int*)l, 16, 0, 0);
}

// ============== merged converter: blocks 0..2047 inputs, 2048..2591 weights ==============
// inputs -> bf16 pre-swizzled ws image (R13 proven body)
// weights -> fragment-linear bf16 (R13 proven body)
__global__ __launch_bounds__(256) void convert_all(
    const float* __restrict__ text, const float* __restrict__ image,
    const float* __restrict__ W1, const float* __restrict__ W2,
    const float* __restrict__ gW1,
    unsigned short* __restrict__ textW, unsigned short* __restrict__ imageW,
    unsigned short* __restrict__ W1L, unsigned short* __restrict__ W2T,
    unsigned short* __restrict__ gW1T)
{
    __shared__ __align__(16) char cbuf[8192];

    if (blockIdx.x < 2048) {
        const int t = threadIdx.x;
        const int tensor = blockIdx.x >> 10;
        const int rb = blockIdx.x & 1023;
        const float* in = tensor ? image : text;
        unsigned short* outp = tensor ? imageW : textW;

        const int row = t >> 2, cq = t & 3;

        for (int s = 0; s < 8; ++s) {
            const float* src = in + ((size_t)rb * 64 + row) * 512 + s * 64 + cq * 16;
            float4 v0 = ((const float4*)src)[0];
            float4 v1 = ((const float4*)src)[1];
            float4 v2 = ((const float4*)src)[2];
            float4 v3 = ((const float4*)src)[3];
            {
                int oct = 2 * cq;
                uint4 p; p.x = pk2(v0.x, v0.y); p.y = pk2(v0.z, v0.w);
                p.z = pk2(v1.x, v1.y); p.w = pk2(v1.z, v1.w);
                *(uint4*)(cbuf + oct * 1024 + ((row * 16) ^ (oct << 4))) = p;
            }
            {
                int oct = 2 * cq + 1;
                uint4 p; p.x = pk2(v2.x, v2.y); p.y = pk2(v2.z, v2.w);
                p.z = pk2(v3.x, v3.y); p.w = pk2(v3.z, v3.w);
                *(uint4*)(cbuf + oct * 1024 + ((row * 16) ^ (oct << 4))) = p;
            }
            __syncthreads();
            unsigned short* dst = outp + ((size_t)rb * 4096 + s * 512 + t * 2) * 8;
            *(uint4*)dst = *(uint4*)(cbuf + t * 32);
            *(uint4*)(dst + 8) = *(uint4*)(cbuf + t * 32 + 16);
            __syncthreads();
        }
        return;
    }

    int t = (blockIdx.x - 2048) * 256 + threadIdx.x;
    if (t < 65536) {
        int l = t & 63, nt = (t >> 6) & 7, step = (t >> 9) & 15, hd = t >> 13;
        int n = nt * 16 + (l & 15);
        int k = step * 32 + 8 * (l >> 4);
        const float* s = W1 + (size_t)hd * 65536 + (size_t)k * 128 + n;
        short8v o;
        #pragma unroll
        for (int j = 0; j < 8; ++j) o[j] = (short)f2bf(s[(size_t)j * 128]);
        *(short8v*)(W1L + (size_t)t * 8) = o;
    } else if (t < 65536 + 8192) {
        int u = t - 65536;
        int l = u & 63, nt = (u >> 6) & 3, kb = (u >> 8) & 3, hd = u >> 10;
        int m = 16 * nt + (l & 15);
        int k = 32 * kb + 8 * (l >> 4);
        const float* s = W2 + (size_t)hd * 8192 + (size_t)k * 64 + m;
        short8v o;
        #pragma unroll
        for (int j = 0; j < 8; ++j) o[j] = (short)f2bf(s[(size_t)j * 64]);
        *(short8v*)(W2T + (size_t)u * 8) = o;
    } else if (t < 65536 + 8192 + 65536) {
        int u = t - 73728;
        int l = u & 63, nt = (u >> 6) & 31, s0 = u >> 11;
        int n = 16 * nt + (l & 15);
        int k = 32 * s0 + 8 * (l >> 4);
        const float* s = gW1 + (size_t)k * 512 + n;
        short8v o;
        #pragma unroll
        for (int j = 0; j < 8; ++j) o[j] = (short)f2bf(s[(size_t)j * 512]);
        *(short8v*)(gW1T + (size_t)u * 8) = o;
    }
}

// ============== fused main: blocks 0..2047 global path (32 rows each, gs -> out),
//                blocks 2048..10239 head path (per_aspect) ==============
// (512,4) -> 64-VGPR cap, spill-free (R18: VGPR=60, WRITE~2KB). Global epilogue
// dumps acc through a 64KB LDS oTile; oTile swizzle includes ((row&1)<<6) so a
// wave's 4 rows split across both bank halves (4-way -> 2-way on the read loop).
__global__ __launch_bounds__(512, 4) void fused_main(
    const unsigned short* __restrict__ textW, const unsigned short* __restrict__ imageW,
    const unsigned short* __restrict__ W1L, const float* __restrict__ b1,
    const float* __restrict__ ln1g, const float* __restrict__ ln1b,
    const unsigned short* __restrict__ W2T, const float* __restrict__ b2,
    const unsigned short* __restrict__ gW1T, const float* __restrict__ gb1,
    const float* __restrict__ glng, const float* __restrict__ glnb,
    const float* __restrict__ gW2, const float* __restrict__ gb2,
    float* __restrict__ out_gs_conflict, float* __restrict__ out_pa)
{
    __shared__ __align__(1024) char smem[79872];

    const int tid = threadIdx.x;
    const int w = tid >> 6, lane = tid & 63, lg = lane >> 4, lc = lane & 15;

    if (blockIdx.x < 2048) {
        // ================= GLOBAL PATH: 32 rows x 512 cols =================
        char* gsm = smem;
        const size_t row0 = (size_t)blockIdx.x * 32;
        const int rb = blockIdx.x >> 1;
        const int half = blockIdx.x & 1;
        const char* gWb = (const char*)gW1T;
        const char* tWb = (const char*)textW + (size_t)rb * 65536;
        const char* iWb = (const char*)imageW + (size_t)rb * 65536;
        float* sStat = (float*)(gsm + 69632);
        float* sDot  = (float*)(gsm + 71680);

#define STAGE(p_, st_) do { \
    char* bb_ = gsm + 4096 + (p_) * 32768 + w * 4096; \
    const char* bs_ = gWb + (size_t)(st_) * 32768 + w * 4096 + lane * 16; \
    glds16(bs_, bb_); glds16(bs_ + 1024, bb_ + 1024); \
    glds16(bs_ + 2048, bb_ + 2048); glds16(bs_ + 3072, bb_ + 3072); \
    if (w < 2) { \
        int stx_ = (st_) & 15; \
        const char* base_ = ((st_) < 16) ? tWb : iWb; \
        int oct_ = (stx_ & 1) * 4 + 2 * w + (lane >> 5); \
        const char* as_ = base_ + (stx_ >> 1) * 8192 + oct_ * 1024 \
                        + (32 * half + (lane & 31)) * 16; \
        glds16(as_, gsm + (p_) * 2048 + w * 1024); \
    } } while (0)

        STAGE(0, 0);
        __syncthreads();

        f32x4 acc[2][4];
        #pragma unroll
        for (int rt = 0; rt < 2; ++rt)
            #pragma unroll
            for (int nt = 0; nt < 4; ++nt) acc[rt][nt] = (f32x4){0.f, 0.f, 0.f, 0.f};

        #pragma unroll 2
        for (int st = 0; st < 32; ++st) {
            const int cur = st & 1;
            char* bufAc = gsm + cur * 2048;
            char* bufBc = gsm + 4096 + cur * 32768;
            if (st < 31) STAGE(cur ^ 1, st + 1);

            const int ob = (st & 1) * 4;
            short8v af[2];
            #pragma unroll
            for (int rt = 0; rt < 2; ++rt)
                af[rt] = *(const short8v*)(bufAc + lg * 512
                            + (16 * rt + (lc ^ (ob + lg))) * 16);
            #pragma unroll
            for (int nt = 0; nt < 4; ++nt) {
                short8v bfv = *(const short8v*)(bufBc + (4 * w + nt) * 1024 + lane * 16);
                acc[0][nt] = __builtin_amdgcn_mfma_f32_16x16x32_bf16(af[0], bfv, acc[0][nt], 0, 0, 0);
                acc[1][nt] = __builtin_amdgcn_mfma_f32_16x16x32_bf16(af[1], bfv, acc[1][nt], 0, 0, 0);
            }
            __syncthreads();
        }
#undef STAGE

        // ---- + gb1, LN stat partials (from regs), then dump acc -> oTile ----
        #pragma unroll
        for (int nt = 0; nt < 4; ++nt) {
            float bv = gb1[64 * w + 16 * nt + lc];
            #pragma unroll
            for (int rt = 0; rt < 2; ++rt)
                #pragma unroll
                for (int reg = 0; reg < 4; ++reg) acc[rt][nt][reg] += bv;
        }
        #pragma unroll
        for (int rt = 0; rt < 2; ++rt)
            #pragma unroll
            for (int reg = 0; reg < 4; ++reg) {
                float s1 = 0.f, s2 = 0.f;
                #pragma unroll
                for (int nt = 0; nt < 4; ++nt) { float v = acc[rt][nt][reg]; s1 += v; s2 += v * v; }
                #pragma unroll
                for (int off = 1; off < 16; off <<= 1) {
                    s1 += __shfl_xor(s1, off, 64);
                    s2 += __shfl_xor(s2, off, 64);
                }
                if (lc == 0) {
                    int rr = 16 * rt + 4 * lg + reg;
                    sStat[(w * 32 + rr) * 2 + 0] = s1;
                    sStat[(w * 32 + rr) * 2 + 1] = s2;
                }
            }
        // dump (A/B buffers retired after final loop barrier)
        #pragma unroll
        for (int rt = 0; rt < 2; ++rt)
            #pragma unroll
            for (int nt = 0; nt < 4; ++nt)
                #pragma unroll
                for (int reg = 0; reg < 4; ++reg) {
                    int row = 16 * rt + 4 * lg + reg;
                    int col = 64 * w + 16 * nt + lc;
                    *(float*)(gsm + row * 2048
                        + ((col * 4) ^ ((row & 7) << 4) ^ ((row & 1) << 6))) = acc[rt][nt][reg];
                }
        __syncthreads();

        // ---- low-register epilogue: thread = (row = tid>>4, part = tid&15) ----
        {
            const int row = tid >> 4, part = tid & 15;
            float s1 = 0.f, s2 = 0.f;
            #pragma unroll
            for (int ww = 0; ww < 8; ++ww) {
                s1 += sStat[(ww * 32 + row) * 2 + 0];
                s2 += sStat[(ww * 32 + row) * 2 + 1];
            }
            float mu = s1 * (1.0f / 512.0f);
            float var = s2 * (1.0f / 512.0f) - mu * mu;
            float rsig = rsqrtf(var + 1e-5f);
            const int swz = ((row & 7) << 4) ^ ((row & 1) << 6);
            float dp0 = 0.f, dp1 = 0.f;
            #pragma unroll 4
            for (int j = 0; j < 32; j += 2) {
                int c0 = part + 16 * j;
                int c1 = part + 16 * (j + 1);
                float v0 = *(const float*)(gsm + row * 2048 + ((c0 * 4) ^ swz));
                float v1 = *(const float*)(gsm + row * 2048 + ((c1 * 4) ^ swz));
                v0 = (v0 - mu) * rsig * glng[c0] + glnb[c0];
                v1 = (v1 - mu) * rsig * glng[c1] + glnb[c1];
                dp0 += gelu_exact(v0) * gW2[c0];
                dp1 += gelu_exact(v1) * gW2[c1];
            }
            float dp = dp0 + dp1;
            #pragma unroll
            for (int off = 1; off < 16; off <<= 1) dp += __shfl_xor(dp, off, 64);
            if (part == 0) sDot[row] = dp;
        }
        __syncthreads();

        if (tid < 32) {
            float z = sDot[tid] + gb2[0];
            out_gs_conflict[row0 + tid] = 1.0f / (1.0f + expf(-z));
        }
        return;
    }

    // ================= HEAD PATH (proven body, bid shifted) =================
    const int bid = blockIdx.x - 2048;
    const int wr = w >> 1, wc = w & 1;
    const int xr = bid & 7;
    const int q = bid >> 3;
    const int hd = q & 7;
    const int rb = ((q >> 3) << 3) | xr;
    const size_t row0 = (size_t)rb * 64;

    const char* W1base = (const char*)W1L + (size_t)hd * 131072;
    const char* tWb = (const char*)textW + (size_t)rb * 65536 + w * 1024 + lane * 16;
    const char* iWb = (const char*)imageW + (size_t)rb * 65536 + w * 1024 + lane * 16;
    float* sS = (float*)(smem + 65536);
    unsigned short* hb = (unsigned short*)(smem + 67584 + w * 1152);

#define STAGE_A(buf_, s_) do { \
    glds16(tWb + (s_) * 8192, (buf_) + w * 2048); \
    glds16(iWb + (s_) * 8192, (buf_) + w * 2048 + 1024); } while (0)
#define STAGE_B(buf_, s_) do { \
    const char* bs_ = W1base + (s_) * 16384 + w * 2048 + lane * 16; \
    glds16(bs_, (buf_) + w * 2048); \
    glds16(bs_ + 1024, (buf_) + w * 2048 + 1024); } while (0)

    STAGE_A(smem, 0);
    STAGE_B(smem + 32768, 0);
    __syncthreads();

    f32x4 acc[2][4];
    #pragma unroll
    for (int rt = 0; rt < 2; ++rt)
        #pragma unroll
        for (int nt = 0; nt < 4; ++nt) acc[rt][nt] = (f32x4){0.f, 0.f, 0.f, 0.f};

    #pragma unroll
    for (int s = 0; s < 8; ++s) {
        const int cur = s & 1;
        char* bufAc = smem + cur * 16384;
        char* bufBc = smem + 32768 + cur * 16384;
        if (s < 7) {
            STAGE_A(smem + (cur ^ 1) * 16384, s + 1);
            STAGE_B(smem + 32768 + (cur ^ 1) * 16384, s + 1);
        }
        #pragma unroll
        for (int kk = 0; kk < 2; ++kk) {
            const int o = kk * 4 + lg;
            short8v afv[2];
            #pragma unroll
            for (int rt = 0; rt < 2; ++rt) {
                const int row = 32 * wr + 16 * rt + lc;
                afv[rt] = *(const short8v*)(bufAc + o * 2048 + ((row * 16) ^ (o << 4)));
            }
            #pragma unroll
            for (int nt = 0; nt < 4; ++nt) {
                short8v bfv = *(const short8v*)(bufBc + kk * 8192 + (4 * wc + nt) * 1024 + lane * 16);
                acc[0][nt] = __builtin_amdgcn_mfma_f32_16x16x32_bf16(afv[0], bfv, acc[0][nt], 0, 0, 0);
                acc[1][nt] = __builtin_amdgcn_mfma_f32_16x16x32_bf16(afv[1], bfv, acc[1][nt], 0, 0, 0);
            }
        }
        __syncthreads();
    }
#undef STAGE_A
#undef STAGE_B

    #pragma unroll
    for (int nt = 0; nt < 4; ++nt) {
        float bv = b1[hd * 128 + 64 * wc + 16 * nt + lc];
        #pragma unroll
        for (int rt = 0; rt < 2; ++rt)
            #pragma unroll
            for (int reg = 0; reg < 4; ++reg) acc[rt][nt][reg] += bv;
    }
    #pragma unroll
    for (int rt = 0; rt < 2; ++rt)
        #pragma unroll
        for (int reg = 0; reg < 4; ++reg) {
            float s1 = 0.f, s2 = 0.f;
            #pragma unroll
            for (int nt = 0; nt < 4; ++nt) { float v = acc[rt][nt][reg]; s1 += v; s2 += v * v; }
            #pragma unroll
            for (int off = 1; off < 16; off <<= 1) {
                s1 += __shfl_xor(s1, off, 64);
                s2 += __shfl_xor(s2, off, 64);
            }
            if (lc == 0) {
                int row = 32 * wr + 16 * rt + 4 * lg + reg;
                sS[(wc * 128 + row) * 2 + 0] = s1;
                sS[(wc * 128 + row) * 2 + 1] = s2;
            }
        }
    __syncthreads();

    float mu[2][4], rsig[2][4];
    #pragma unroll
    for (int rt = 0; rt < 2; ++rt)
        #pragma unroll
        for (int reg = 0; reg < 4; ++reg) {
            int row = 32 * wr + 16 * rt + 4 * lg + reg;
            float s1 = sS[row * 2 + 0] + sS[(128 + row) * 2 + 0];
            float s2 = sS[row * 2 + 1] + sS[(128 + row) * 2 + 1];
            float m = s1 * (1.0f / 128.0f);
            float var = s2 * (1.0f / 128.0f) - m * m;
            mu[rt][reg] = m;
            rsig[rt][reg] = rsqrtf(var + 1e-5f);
        }
    #pragma unroll
    for (int nt = 0; nt < 4; ++nt) {
        int col = 64 * wc + 16 * nt + lc;
        float gv = ln1g[hd * 128 + col];
        float bv = ln1b[hd * 128 + col];
        #pragma unroll
        for (int rt = 0; rt < 2; ++rt)
            #pragma unroll
            for (int reg = 0; reg < 4; ++reg) {
                float v = (acc[rt][nt][reg] - mu[rt][reg]) * rsig[rt][reg] * gv + bv;
                acc[rt][nt][reg] = gelu_exact(v);
            }
    }

    const char* W2b = (const char*)W2T + (size_t)hd * 16384;
    #pragma unroll
    for (int rt = 0; rt < 2; ++rt) {
        f32x4 acc2[4];
        #pragma unroll
        for (int nt2 = 0; nt2 < 4; ++nt2) acc2[nt2] = (f32x4){0.f, 0.f, 0.f, 0.f};

        #pragma unroll
        for (int kk2 = 0; kk2 < 2; ++kk2) {
            #pragma unroll
            for (int ntl = 0; ntl < 2; ++ntl) {
                const int nt = 2 * kk2 + ntl;
                const int kk = 16 * ntl + lc;
                #pragma unroll
                for (int reg = 0; reg < 4; ++reg)
                    hb[(4 * lg + reg) * 36 + kk] = f2bf(acc[rt][nt][reg]);
            }
            short8v af2 = *(const short8v*)((const char*)hb + lc * 72 + 16 * lg);
            const char* wb = W2b + (2 * wc + kk2) * 4096 + lane * 16;
            #pragma unroll
            for (int nt2 = 0; nt2 < 4; ++nt2) {
                short8v w2f = *(const short8v*)(wb + nt2 * 1024);
                acc2[nt2] = __builtin_amdgcn_mfma_f32_16x16x32_bf16(af2, w2f, acc2[nt2], 0, 0, 0);
            }
        }
        if (wc == 0) {
            #pragma unroll
            for (int nt2 = 0; nt2 < 4; ++nt2) {
                float bv = b2[hd * 64 + 16 * nt2 + lc];
                #pragma unroll
                for (int reg = 0; reg < 4; ++reg) {
                    int row = 32 * wr + 16 * rt + 4 * lg + reg;
                    int col = 16 * nt2 + lc;
                    *(float*)(smem + row * 256 + ((col * 4) ^ ((row & 7) << 4))) = acc2[nt2][reg] + bv;
                }
            }
        }
        __syncthreads();
        if (wc == 1) {
            #pragma unroll
            for (int nt2 = 0; nt2 < 4; ++nt2)
                #pragma unroll
                for (int reg = 0; reg < 4; ++reg) {
                    int row = 32 * wr + 16 * rt + 4 * lg + reg;
                    int col = 16 * nt2 + lc;
                    float* p = (float*)(smem + row * 256 + ((col * 4) ^ ((row & 7) << 4)));
                    *p += acc2[nt2][reg];
                }
        }
        __syncthreads();
    }

    if (w < 4) {
        int r = 16 * w + lc;
        int sw = (r & 7) << 4;
        float nt_ = 0.f, ni_ = 0.f, pr = 0.f;
        #pragma unroll
        for (int q2 = 0; q2 < 4; ++q2) {
            int c16 = 2 * lg + (q2 & 1) + (q2 >> 1) * 8;
            float4 a = *(const float4*)(smem + r * 256 + ((c16 * 16) ^ sw));
            float4 b = *(const float4*)(smem + (r + 64) * 256 + ((c16 * 16) ^ sw));
            nt_ += a.x * a.x + a.y * a.y + a.z * a.z + a.w * a.w;
            ni_ += b.x * b.x + b.y * b.y + b.z * b.z + b.w * b.w;
            pr  += a.x * b.x + a.y * b.y + a.z * b.z + a.w * b.w;
        }
        nt_ += __shfl_xor(nt_, 16, 64); ni_ += __shfl_xor(ni_, 16, 64); pr += __shfl_xor(pr, 16, 64);
        nt_ += __shfl_xor(nt_, 32, 64); ni_ += __shfl_xor(ni_, 32, 64); pr += __shfl_xor(pr, 32, 64);
        if (lg == 0) {
            float denom = fmaxf(sqrtf(nt_), 1e-12f) * fmaxf(sqrtf(ni_), 1e-12f);
            out_pa[(row0 + r) * 8 + hd] = pr / denom;
        }
    }
}

// ============== finalize: conflict = clip(1 - 0.7*softmax(aw)@pa - 0.3*gs) ==============
__global__ __launch_bounds__(256) void finalize(
    const float* __restrict__ aw, const float* __restrict__ pa,
    float* __restrict__ out_conflict)
{
    int r = blockIdx.x * 256 + threadIdx.x;
    float wv[8], mx = -1e30f;
    #pragma unroll
    for (int i = 0; i < 8; ++i) { wv[i] = aw[i]; mx = fmaxf(mx, wv[i]); }
    float sum = 0.f;
    #pragma unroll
    for (int i = 0; i < 8; ++i) { wv[i] = __expf(wv[i] - mx); sum += wv[i]; }
    float inv = __builtin_amdgcn_rcpf(sum);
    const float* par = pa + (size_t)r * 8;
    float4 p0 = ((const float4*)par)[0];
    float4 p1 = ((const float4*)par)[1];
    float wsim = p0.x * wv[0] + p0.y * wv[1] + p0.z * wv[2] + p0.w * wv[3]
               + p1.x * wv[4] + p1.y * wv[5] + p1.z * wv[6] + p1.w * wv[7];
    wsim *= inv;
    float gs = out_conflict[r];
    float conf = 1.0f - (0.7f * wsim + 0.3f * gs);
    out_conflict[r] = fminf(fmaxf(conf, 0.0f), 1.0f);
}

extern "C" void kernel_launch(void* const* d_in, const int* in_sizes, int n_in,
                              void* d_out, int out_size, void* d_ws, size_t ws_size,
                              hipStream_t stream) {
    const float* text  = (const float*)d_in[0];
    const float* image = (const float*)d_in[1];
    const float* W1    = (const float*)d_in[2];
    const float* b1    = (const float*)d_in[3];
    const float* ln1g  = (const float*)d_in[4];
    const float* ln1b  = (const float*)d_in[5];
    const float* W2    = (const float*)d_in[6];
    const float* b2    = (const float*)d_in[7];
    const float* aw    = (const float*)d_in[8];
    const float* gW1   = (const float*)d_in[9];
    const float* gb1   = (const float*)d_in[10];
    const float* glng  = (const float*)d_in[11];
    const float* glnb  = (const float*)d_in[12];
    const float* gW2   = (const float*)d_in[13];
    const float* gb2   = (const float*)d_in[14];

    float* out = (float*)d_out;
    float* out_pa = out + B_TOTAL;

    unsigned short* textW  = (unsigned short*)d_ws;                           // 64MB
    unsigned short* imageW = (unsigned short*)((char*)d_ws + 67108864);       // 64MB
    unsigned short* W1L    = (unsigned short*)((char*)d_ws + 134217728);      // 1MB
    unsigned short* W2T    = (unsigned short*)((char*)d_ws + 135266304);      // 128KB
    unsigned short* gW1T   = (unsigned short*)((char*)d_ws + 135397376);      // 1MB

    convert_all<<<2592, 256, 0, stream>>>(text, image, W1, W2, gW1,
                                          textW, imageW, W1L, W2T, gW1T);
    fused_main<<<10240, 512, 0, stream>>>(textW, imageW, W1L, b1, ln1g, ln1b, W2T, b2,
                                          gW1T, gb1, glng, glnb, gW2, gb2,
                                          out, out_pa);
    finalize<<<256, 256, 0, stream>>>(aw, out_pa, out);
}